// Round 15
// baseline (123.999 us; speedup 1.0000x reference)
//
#include <hip/hip_runtime.h>
#include <math.h>

#define N_ROWS  32768
#define K_CODES 1024
#define D_DIM   64
#define C_SHIFT 30.0f        // logit shift keeps exp2 in fp32 range
#define LOG2E_F 1.4426950408889634f
#define LN2_F   0.6931471805599453f
#define TAU     0.25f        // rescue threshold (base-2 logit units)

// ---- ws float-index layout (only WS_CNT needs zeroing, done by prep) ----
#define WS_CNT    0                       // hist_fin completion counter (int)
#define WS_E2C    6144                    // [1024] ||e||^2 + C_SHIFT (legacy order)
#define CHUNK_F4  260                     // float4s per chunk record
#define ALL_CHUNKS 64                     // 16-code chunks, full K
#define WS_EB      8192                        // 64 chunks x 260 f4
#define WS_GP      (WS_EB + 64 * CHUNK_F4 * 4) // 74752; 16 x 4096 gram partials
#define WS_HB      (WS_GP + 16 * 4096)         // 140288; 16 x 1024 hist partials
#define WS_PH      (WS_HB + 16 * K_CODES)      // 156672; 512 entropy partials
#define WS_PC      (WS_PH + 512)               // 157184; 512 commit partials

// ---- out float-index layout (reference return order, concatenated) ----
#define OUT_Q      0
#define OUT_COMMIT 2097152
#define OUT_ORTHO  2097153
#define OUT_ENT    2097154
#define OUT_PERP   2097155
#define OUT_COV    2097156
#define OUT_IDX    2097157

typedef __attribute__((ext_vector_type(8))) _Float16 f16x8;  // 8 f16 = 4 VGPR
typedef __attribute__((ext_vector_type(4))) float f32x4;

__device__ inline unsigned umaxu(unsigned a, unsigned b) { return a > b ? a : b; }
__device__ inline unsigned uminu(unsigned a, unsigned b) { return a < b ? a : b; }

// inverse of the monotone float->u32 map (for TAU screening)
__device__ inline float keyval(unsigned u) {
    unsigned b = (u & 0x80000000u) ? (u ^ 0x80000000u) : ~u;
    return __uint_as_float(b);
}

// fp16x2 decomposition of 8 floats -> (hi, mid) f16x8 pair.
__device__ inline void decomp2x8(const float* v, f16x8& h, f16x8& m) {
#pragma unroll
    for (int i = 0; i < 8; ++i) {
        _Float16 hh = (_Float16)v[i];
        h[i] = hh;
        m[i] = (_Float16)(v[i] - (float)hh);
    }
}

// Blocks 0..15: E-fragment fp16x2 decomposition + ||e||^2.
// Blocks 16..31: ortho gram partials -> per-block slots (non-atomic).
__global__ __launch_bounds__(256) void vq_prep_ortho(const float* __restrict__ emb,
                                                     const float* __restrict__ cc,
                                                     float* __restrict__ ws) {
    __shared__ float srows[64][64];
    __shared__ float rn2[64];
    const int t = threadIdx.x;

    if (blockIdx.x < 16) {
        if (blockIdx.x == 0 && t == 0) ((int*)ws)[WS_CNT] = 0;  // hist_fin counter

        const int tid  = blockIdx.x * 256 + t;            // 0..4095
        const int c    = tid >> 6;
        const int lane = tid & 63;
        const int col  = lane & 15;
        const int kg   = lane >> 4;
        const int code = c * 16 + col;
        float4* EB4 = (float4*)(ws + WS_EB);
#pragma unroll
        for (int s = 0; s < 2; ++s) {
            const float* ep = emb + (size_t)code * D_DIM + s * 32 + kg * 8;
            float4 A4 = *(const float4*)ep;
            float4 B4 = *(const float4*)(ep + 4);
            float v[8] = {A4.x, A4.y, A4.z, A4.w, B4.x, B4.y, B4.z, B4.w};
            union { f16x8 h; float4 f; } th, tm;
            decomp2x8(v, th.h, tm.h);
            const int base = c * CHUNK_F4;
            EB4[base + (s * 2 + 0) * 64 + lane] = th.f;   // hi  frag, k-step s
            EB4[base + (s * 2 + 1) * 64 + lane] = tm.f;   // mid frag, k-step s
        }
        if (kg == 0) {
            // legacy sequential order -> ws[WS_E2C] bitwise matches prior rounds
            const float4* e4 = (const float4*)(emb + (size_t)code * D_DIM);
            float ssum = 0.f;
#pragma unroll
            for (int j = 0; j < 16; ++j) {
                float4 v = e4[j];
                ssum += v.x * v.x + v.y * v.y + v.z * v.z + v.w * v.w;
            }
            float e2c = ssum + C_SHIFT;
            ws[WS_E2C + code] = e2c;
            ((float*)(EB4 + c * CHUNK_F4 + 256))[col] = e2c * LOG2E_F;  // base-2
        }
        return;
    }

    // ---- ortho: block b owns codes [64b, 64b+64); partial 64x64 gram
    const int ob = blockIdx.x - 16;
    const int k0 = ob * 64;
    const int rb = t >> 4;            // 0..15
    const int c4 = (t & 15) << 2;     // float4 col

#pragma unroll
    for (int i = 0; i < 4; ++i) {
        const int r = i * 16 + rb;
        float4 v = *(const float4*)(emb + (size_t)(k0 + r) * D_DIM + c4);
        *(float4*)(&srows[r][c4]) = v;
        float ss = v.x * v.x + v.y * v.y + v.z * v.z + v.w * v.w;
        ss += __shfl_down(ss, 8, 16);
        ss += __shfl_down(ss, 4, 16);
        ss += __shfl_down(ss, 2, 16);
        ss += __shfl_down(ss, 1, 16);
        if ((t & 15) == 0) {
            float nrm = fmaxf(sqrtf(ss), 1e-12f);
            float m = (cc[k0 + r] >= 1.0f) ? 1.0f : 0.0f;
            rn2[r] = m / (nrm * nrm);     // rnorm^2, folded into A side
        }
    }
    __syncthreads();

    const int a  = t >> 2;
    const int b0 = (t & 3) << 4;
    float acc[16];
#pragma unroll
    for (int i = 0; i < 16; ++i) acc[i] = 0.f;

#pragma unroll 4
    for (int k = 0; k < 64; ++k) {
        float na = srows[k][a] * rn2[k];
        const float* rbp = &srows[k][b0];
#pragma unroll
        for (int i = 0; i < 16; ++i) acc[i] = fmaf(na, rbp[i], acc[i]);
    }
#pragma unroll
    for (int i = 0; i < 16; ++i)
        ws[WS_GP + ob * 4096 + a * 64 + b0 + i] = acc[i];   // own slot, no atomic
}

#define MFMA_F16 __builtin_amdgcn_mfma_f32_16x16x32_f16

// 512 blocks x 256 thr. Block = 64 rows x ALL 1024 codes (full-K fusion:
// no combine stage, no partials round-trip). Wave = 16 rows x 1024 codes,
// 64 chunks via the r14 triple-buffer LDS staging (distance-2 prefetch
// covers latency at the forced 2 waves/SIMD -- r5-vs-r9 showed 2 vs 8
// waves/SIMD differ <2us on this loop). Top-2 kept PER 256-CODE QUARTER
// (flushed to LDS at chunks 15/31/47/63): 8 candidates/row with 8-bit
// embeds + TAU screen == round-11's proven per-split semantics. Tail:
// quad-per-row exact fp32 rescue (bit-identical legacy chains), Q-write,
// commitment, entropy -- all in-block.
__global__ __launch_bounds__(256)
void vq_main(const float* __restrict__ inp, const float* __restrict__ emb,
             float* __restrict__ ws, float* __restrict__ out) {
    __shared__ float4 sbuf[3][256];          // 12 KB chunk triple-buffer
    __shared__ unsigned cK[4][16][4][2];     // [wave][row][quarter][rank]
    __shared__ float sS[4][16], sU[4][16];
    __shared__ float shH[4], shC[4];
    const int t    = threadIdx.x;
    const int lane = t & 63;
    const int wave = t >> 6;
    const int col  = lane & 15;
    const int kg   = lane >> 4;
    const int rg   = blockIdx.x;             // row group 0..511 (64 rows)
    const int row  = rg * 64 + wave * 16 + col;

    // A-frags: hi/mid per k-step
    f16x8 xh0, xm0, xh1, xm1;
    {
        const float* xp = inp + (size_t)row * D_DIM + kg * 8;
        float4 A4 = *(const float4*)xp;
        float4 B4 = *(const float4*)(xp + 4);
        float v[8] = {A4.x, A4.y, A4.z, A4.w, B4.x, B4.y, B4.z, B4.w};
        decomp2x8(v, xh0, xm0);
        A4 = *(const float4*)(xp + 32);
        B4 = *(const float4*)(xp + 36);
        float w[8] = {A4.x, A4.y, A4.z, A4.w, B4.x, B4.y, B4.z, B4.w};
        decomp2x8(w, xh1, xm1);
    }

    const float4* EBp = (const float4*)(ws + WS_EB);

    float sa[4], ua[4];
    unsigned m1[4], m2[4];
#pragma unroll
    for (int q = 0; q < 4; ++q) {
        sa[q] = 0.f; ua[q] = 0.f;
        m1[q] = 0u; m2[q] = 0u;     // below any finite key
    }

    // prologue: stage chunks 0 and 1
    sbuf[0][t] = EBp[t];
    sbuf[1][t] = EBp[CHUNK_F4 + t];

#pragma unroll 1
    for (int c = 0; c < ALL_CHUNKS; ++c) {
        __syncthreads();                    // buf[c%3] staged & visible;
                                            // all reads of buf[(c+2)%3] done
        // T14 issue-early: in-flight load for chunk c+2 (written at bottom)
        float4 gn;
        if (c + 2 < ALL_CHUNKS) gn = EBp[(size_t)(c + 2) * CHUNK_F4 + t];

        const f16x8* pb = (const f16x8*)&sbuf[c % 3][0];
        const float e2v = ((const float*)(EBp + (size_t)c * CHUNK_F4 + 256))[col];

        f32x4 acc = {0.f, 0.f, 0.f, 0.f};
        {   // k-step 0: 2 live B-frags
            f16x8 bh0 = pb[0 * 64 + lane];
            f16x8 bm0 = pb[1 * 64 + lane];
            acc = MFMA_F16(xh0, bh0, acc, 0, 0, 0);
            acc = MFMA_F16(xm0, bh0, acc, 0, 0, 0);
            acc = MFMA_F16(xh0, bm0, acc, 0, 0, 0);
            acc = MFMA_F16(xm0, bm0, acc, 0, 0, 0);
        }
        {   // k-step 1
            f16x8 bh1 = pb[2 * 64 + lane];
            f16x8 bm1 = pb[3 * 64 + lane];
            acc = MFMA_F16(xh1, bh1, acc, 0, 0, 0);
            acc = MFMA_F16(xm1, bh1, acc, 0, 0, 0);
            acc = MFMA_F16(xh1, bm1, acc, 0, 0, 0);
            acc = MFMA_F16(xm1, bm1, acc, 0, 0, 0);
        }

        // embed: quarter-local code = (c&15)*16+col in [0,256), inverted so
        // smaller code -> larger key -> legacy first-index ties (== r11)
        const unsigned embedv = 255u - (unsigned)((c & 15) * 16 + col);
#pragma unroll
        for (int q = 0; q < 4; ++q) {
            // base-2 shifted logit: g = 2*log2e*dot - log2e*(e2+C_SHIFT)
            float g = fmaf(2.0f * LOG2E_F, acc[q], -e2v);
            float pw;
            asm("v_exp_f32 %0, %1" : "=v"(pw) : "v"(g));   // 2^g
            sa[q] += pw;
            ua[q] = fmaf(pw, g, ua[q]);
            int gb = __float_as_int(g);
            unsigned u = (unsigned)(gb ^ ((gb >> 31) | 0x80000000));
            unsigned key = (u & 0xFFFFFF00u) | embedv;
            m2[q] = uminu(umaxu(key, m2[q]), m1[q]);   // med3(key, m2, m1)
            m1[q] = umaxu(m1[q], key);
        }

        // quarter boundary: merge keys across the 16 code-lanes, flush, reset
        if ((c & 15) == 15) {
            const int qt = c >> 4;
#pragma unroll
            for (int off = 1; off < 16; off <<= 1) {
#pragma unroll
                for (int q = 0; q < 4; ++q) {
                    unsigned p1 = (unsigned)__shfl_xor((int)m1[q], off);
                    unsigned p2 = (unsigned)__shfl_xor((int)m2[q], off);
                    unsigned lo = uminu(m1[q], p1);
                    m1[q] = umaxu(m1[q], p1);
                    m2[q] = umaxu(lo, umaxu(m2[q], p2));
                }
            }
            if (col == 0) {
#pragma unroll
                for (int q = 0; q < 4; ++q) {
                    cK[wave][kg * 4 + q][qt][0] = m1[q];
                    cK[wave][kg * 4 + q][qt][1] = m2[q];
                }
            }
#pragma unroll
            for (int q = 0; q < 4; ++q) { m1[q] = 0u; m2[q] = 0u; }
        }

        // T14 write-late: land the staged chunk (buffer free since barrier)
        if (c + 2 < ALL_CHUNKS) sbuf[(c + 2) % 3][t] = gn;
    }

    // softmax sums: reduce across the 16 code-lanes, hand off via LDS
#pragma unroll
    for (int off = 1; off < 16; off <<= 1) {
#pragma unroll
        for (int q = 0; q < 4; ++q) {
            sa[q] += __shfl_xor(sa[q], off);
            ua[q] += __shfl_xor(ua[q], off);
        }
    }
    if (col == 0) {
#pragma unroll
        for (int q = 0; q < 4; ++q) {
            sS[wave][kg * 4 + q] = sa[q];
            sU[wave][kg * 4 + q] = ua[q];
        }
    }
    __syncthreads();

    // ---- tail: quad-per-row finalize (== r11 combine, LDS-sourced) ----
    const int l    = t & 3;                // quad lane = legacy chain id
    const int rloc = (t >> 2) & 15;
    const int wsrc = t >> 6;
    const int frow = rg * 64 + wsrc * 16 + rloc;
    const int qb   = lane & ~3;

    float S  = sS[wsrc][rloc];
    float U2 = sU[wsrc][rloc];

    float Gmax = -1e30f;
#pragma unroll
    for (int qt = 0; qt < 4; ++qt)
        Gmax = fmaxf(Gmax, keyval(cK[wsrc][rloc][qt][0]));

    // X strided quarter: Xq[k] = X[l + 4k]
    float4 Xq[4];
    const float4* xr = (const float4*)(inp + (size_t)frow * D_DIM);
#pragma unroll
    for (int k = 0; k < 4; ++k) Xq[k] = xr[l + 4 * k];

    // candidates in legacy order (quarter asc, rank-1 before rank-2)
    float bestg = -1e30f; int I = K_CODES;
#pragma unroll 1
    for (int j = 0; j < 8; ++j) {
        const unsigned kk = cK[wsrc][rloc][j >> 1][j & 1];
        const float v = keyval(kk);
        if (v < Gmax - TAU) continue;      // provably cannot be exact argmax
        const int c = (j >> 1) * 256 + 255 - (int)(kk & 255u);
        const float4* e4 = (const float4*)(emb + (size_t)c * D_DIM);
        float d = 0.f;
#pragma unroll
        for (int k = 0; k < 4; ++k) {
            float4 ev = e4[l + 4 * k];
            float4 xv = Xq[k];
            d = fmaf(ev.x, xv.x, d); d = fmaf(ev.y, xv.y, d);
            d = fmaf(ev.z, xv.z, d); d = fmaf(ev.w, xv.w, d);
        }
        float dA = __shfl(d, qb + 0) + __shfl(d, qb + 1);   // (d0+d1)
        float dB = __shfl(d, qb + 2) + __shfl(d, qb + 3);   // (d2+d3)
        float g  = fmaf(2.0f, dA + dB, -ws[WS_E2C + c]);    // legacy-exact
        if (g > bestg || (g == bestg && c < I)) { bestg = g; I = c; }
    }

    float H = logf(S) - (U2 * LN2_F) / S;  // per-row entropy (nats)

    if (l == 0) out[OUT_IDX + frow] = (float)I;

    // quantized + commitment on the strided quarter (elementwise-identical Q)
    const float4* q4 = (const float4*)(emb + (size_t)I * D_DIM);
    float4* oq = (float4*)out + (size_t)frow * 16;
    float cs = 0.f;
#pragma unroll
    for (int k = 0; k < 4; ++k) {
        float4 q = q4[l + 4 * k], x = Xq[k];
        float dx = q.x - x.x, dy = q.y - x.y, dz = q.z - x.z, dw = q.w - x.w;
        cs += dx * dx + dy * dy + dz * dz + dw * dw;
        float4 o;
        o.x = x.x + dx; o.y = x.y + dy; o.z = x.z + dz; o.w = x.w + dw;
        oq[l + 4 * k] = o;
    }

    float Hc = (l == 0) ? H : 0.f;
#pragma unroll
    for (int off = 32; off; off >>= 1) {
        Hc += __shfl_down(Hc, off);
        cs += __shfl_down(cs, off);
    }
    if (lane == 0) { shH[wave] = Hc; shC[wave] = cs; }
    __syncthreads();
    if (t == 0) {
        ws[WS_PH + blockIdx.x] = shH[0] + shH[1] + shH[2] + shH[3];
        ws[WS_PC + blockIdx.x] = shC[0] + shC[1] + shC[2] + shC[3];
    }
}

// 16 blocks x 256 thr; block b LDS-histograms rows [2048b, 2048b+2048) from
// OUT_IDX -> private partial slot. LAST block (16-block counter) runs the
// finalize with agent-scope loads.
__global__ __launch_bounds__(256) void vq_hist_fin(const float* __restrict__ cc,
                                                   float* __restrict__ ws,
                                                   float* __restrict__ out) {
    __shared__ int h[K_CODES];
    __shared__ int lastFlag;
    __shared__ float red[5][4];
    const int t = threadIdx.x;
#pragma unroll
    for (int i = 0; i < 4; ++i) h[t + 256 * i] = 0;
    __syncthreads();
    const int base = blockIdx.x * 2048;
#pragma unroll
    for (int i = 0; i < 8; ++i) {
        int idx = (int)out[OUT_IDX + base + t + 256 * i];
        atomicAdd(&h[idx], 1);                          // LDS atomic only
    }
    __syncthreads();
#pragma unroll
    for (int i = 0; i < 4; ++i) {
        const int k = t + 256 * i;
        ws[WS_HB + blockIdx.x * K_CODES + k] = (float)h[k];
    }
    __threadfence();                                    // partial visible device-wide
    __syncthreads();
    if (t == 0) {
        int old = __hip_atomic_fetch_add((int*)ws + WS_CNT, 1,
                                         __ATOMIC_ACQ_REL,
                                         __HIP_MEMORY_SCOPE_AGENT);
        lastFlag = (old == 15);
    }
    __syncthreads();
    if (!lastFlag) return;

    // ---- last block: finalize ----
    float hp = 0.f, gg = 0.f, nu = 0.f, hh = 0.f, cm = 0.f;
    for (int k = t; k < K_CODES; k += 256) {
        float s = 0.f;
#pragma unroll
        for (int b = 0; b < 16; ++b)
            s += __hip_atomic_load(ws + WS_HB + b * K_CODES + k,
                                   __ATOMIC_RELAXED, __HIP_MEMORY_SCOPE_AGENT);
        float p = s * (1.0f / (float)N_ROWS);
        hp += p * logf(p + 1e-10f);
        nu += (cc[k] >= 1.0f) ? 1.0f : 0.0f;
    }
    for (int i = t; i < 4096; i += 256) {              // prior dispatch: plain loads
        float s = 0.f;
#pragma unroll
        for (int b = 0; b < 16; ++b) s += ws[WS_GP + b * 4096 + i];
        gg = fmaf(s, s, gg);
    }
    for (int i = t; i < 512; i += 256) {               // prior dispatch
        hh += ws[WS_PH + i];
        cm += ws[WS_PC + i];
    }
#pragma unroll
    for (int off = 32; off; off >>= 1) {
        hp += __shfl_down(hp, off);
        gg += __shfl_down(gg, off);
        nu += __shfl_down(nu, off);
        hh += __shfl_down(hh, off);
        cm += __shfl_down(cm, off);
    }
    if ((t & 63) == 0) {
        const int w = t >> 6;
        red[0][w] = hp; red[1][w] = gg; red[2][w] = nu;
        red[3][w] = hh; red[4][w] = cm;
    }
    __syncthreads();
    if (t == 0) {
        float hsum = red[0][0] + red[0][1] + red[0][2] + red[0][3];
        float gsum = red[1][0] + red[1][1] + red[1][2] + red[1][3];
        float nuv  = red[2][0] + red[2][1] + red[2][2] + red[2][3];
        float hacc = red[3][0] + red[3][1] + red[3][2] + red[3][3];
        float cacc = red[4][0] + red[4][1] + red[4][2] + red[4][3];
        out[OUT_PERP]   = expf(-hsum);
        out[OUT_ENT]    = hacc * (1.0f / (float)N_ROWS) * 0.1f; // /log2(1024)
        out[OUT_COMMIT] = cacc * (1.0f / ((float)N_ROWS * (float)D_DIM));
        out[OUT_ORTHO]  = gsum / (nuv * nuv) - 1.0f / nuv;
        out[OUT_COV]    = nuv * (1.0f / (float)K_CODES);
    }
}

extern "C" void kernel_launch(void* const* d_in, const int* in_sizes, int n_in,
                              void* d_out, int out_size, void* d_ws, size_t ws_size,
                              hipStream_t stream) {
    const float* inp = (const float*)d_in[0];   // [16,2048,64]
    const float* emb = (const float*)d_in[1];   // [1024,64]
    const float* cc  = (const float*)d_in[2];   // [1024]
    float* out = (float*)d_out;
    float* ws  = (float*)d_ws;

    vq_prep_ortho<<<32, 256, 0, stream>>>(emb, cc, ws);
    vq_main<<<N_ROWS / 64, 256, 0, stream>>>(inp, emb, ws, out);
    vq_hist_fin<<<16, 256, 0, stream>>>(cc, ws, out);
}

// Round 16
// 118.520 us; speedup vs baseline: 1.0462x; 1.0462x over previous
//
#include <hip/hip_runtime.h>
#include <math.h>

#define N_ROWS  32768
#define K_CODES 1024
#define D_DIM   64
#define NSPLIT  4            // K-splits (256 codes each)
#define C_SHIFT 30.0f        // logit shift keeps exp2 in fp32 range
#define LOG2E_F 1.4426950408889634f
#define LN2_F   0.6931471805599453f
#define TAU     0.25f        // rescue threshold (base-2 logit units)

// ---- ws float-index layout (NO region needs pre-zeroing) ----
#define WS_E2C    6144                    // [1024] ||e||^2 + C_SHIFT (legacy order)
#define PART_STRIDE (NSPLIT * N_ROWS)     // 131072
#define WS_PART_S  8192
#define WS_PART_U  (8192 + PART_STRIDE)
#define WS_PART_M1 (8192 + 2 * PART_STRIDE)   // top-1 key (u32 bits in float slot)
#define WS_PART_M2 (8192 + 3 * PART_STRIDE)   // top-2 key
#define CHUNK_F4  260                     // float4s per chunk record
#define MAIN_CHUNKS 16                    // 16-code chunks per K-split
#define WS_EB      (8192 + 4 * PART_STRIDE)    // 532480; 64 chunks x 260 f4
#define WS_GP      (WS_EB + 64 * CHUNK_F4 * 4) // 599040; 16 x 4096 gram partials
#define WS_HB      (WS_GP + 16 * 4096)         // 664576; 16 x 1024 hist partials
#define WS_PH      (WS_HB + 16 * K_CODES)      // 680960; 512 entropy partials
#define WS_PC      (WS_PH + 512)               // 681472; 512 commit partials

// ---- out float-index layout (reference return order, concatenated) ----
#define OUT_Q      0
#define OUT_COMMIT 2097152
#define OUT_ORTHO  2097153
#define OUT_ENT    2097154
#define OUT_PERP   2097155
#define OUT_COV    2097156
#define OUT_IDX    2097157

typedef __attribute__((ext_vector_type(8))) _Float16 f16x8;  // 8 f16 = 4 VGPR
typedef __attribute__((ext_vector_type(4))) float f32x4;

__device__ inline unsigned umaxu(unsigned a, unsigned b) { return a > b ? a : b; }
__device__ inline unsigned uminu(unsigned a, unsigned b) { return a < b ? a : b; }

// inverse of the monotone float->u32 map (for TAU screening in combine)
__device__ inline float keyval(unsigned u) {
    unsigned b = (u & 0x80000000u) ? (u ^ 0x80000000u) : ~u;
    return __uint_as_float(b);
}

// fp16x2 decomposition of 8 floats -> (hi, mid) f16x8 pair.
__device__ inline void decomp2x8(const float* v, f16x8& h, f16x8& m) {
#pragma unroll
    for (int i = 0; i < 8; ++i) {
        _Float16 hh = (_Float16)v[i];
        h[i] = hh;
        m[i] = (_Float16)(v[i] - (float)hh);
    }
}

// Blocks 0..15: E-fragment fp16x2 decomposition + ||e||^2.
// Blocks 16..31: ortho gram partials -> per-block slots (non-atomic).
__global__ __launch_bounds__(256) void vq_prep_ortho(const float* __restrict__ emb,
                                                     const float* __restrict__ cc,
                                                     float* __restrict__ ws) {
    __shared__ float srows[64][64];
    __shared__ float rn2[64];
    const int t = threadIdx.x;

    if (blockIdx.x < 16) {
        const int tid  = blockIdx.x * 256 + t;            // 0..4095
        const int c    = tid >> 6;
        const int lane = tid & 63;
        const int col  = lane & 15;
        const int kg   = lane >> 4;
        const int code = c * 16 + col;
        float4* EB4 = (float4*)(ws + WS_EB);
#pragma unroll
        for (int s = 0; s < 2; ++s) {
            const float* ep = emb + (size_t)code * D_DIM + s * 32 + kg * 8;
            float4 A4 = *(const float4*)ep;
            float4 B4 = *(const float4*)(ep + 4);
            float v[8] = {A4.x, A4.y, A4.z, A4.w, B4.x, B4.y, B4.z, B4.w};
            union { f16x8 h; float4 f; } th, tm;
            decomp2x8(v, th.h, tm.h);
            const int base = c * CHUNK_F4;
            EB4[base + (s * 2 + 0) * 64 + lane] = th.f;   // hi  frag, k-step s
            EB4[base + (s * 2 + 1) * 64 + lane] = tm.f;   // mid frag, k-step s
        }
        if (kg == 0) {
            // legacy sequential order -> ws[WS_E2C] bitwise matches prior rounds
            const float4* e4 = (const float4*)(emb + (size_t)code * D_DIM);
            float ssum = 0.f;
#pragma unroll
            for (int j = 0; j < 16; ++j) {
                float4 v = e4[j];
                ssum += v.x * v.x + v.y * v.y + v.z * v.z + v.w * v.w;
            }
            float e2c = ssum + C_SHIFT;
            ws[WS_E2C + code] = e2c;
            ((float*)(EB4 + c * CHUNK_F4 + 256))[col] = e2c * LOG2E_F;  // base-2
        }
        return;
    }

    // ---- ortho: block b owns codes [64b, 64b+64); partial 64x64 gram
    const int ob = blockIdx.x - 16;
    const int k0 = ob * 64;
    const int rb = t >> 4;            // 0..15
    const int c4 = (t & 15) << 2;     // float4 col

#pragma unroll
    for (int i = 0; i < 4; ++i) {
        const int r = i * 16 + rb;
        float4 v = *(const float4*)(emb + (size_t)(k0 + r) * D_DIM + c4);
        *(float4*)(&srows[r][c4]) = v;
        float ss = v.x * v.x + v.y * v.y + v.z * v.z + v.w * v.w;
        ss += __shfl_down(ss, 8, 16);
        ss += __shfl_down(ss, 4, 16);
        ss += __shfl_down(ss, 2, 16);
        ss += __shfl_down(ss, 1, 16);
        if ((t & 15) == 0) {
            float nrm = fmaxf(sqrtf(ss), 1e-12f);
            float m = (cc[k0 + r] >= 1.0f) ? 1.0f : 0.0f;
            rn2[r] = m / (nrm * nrm);     // rnorm^2, folded into A side
        }
    }
    __syncthreads();

    const int a  = t >> 2;
    const int b0 = (t & 3) << 4;
    float acc[16];
#pragma unroll
    for (int i = 0; i < 16; ++i) acc[i] = 0.f;

#pragma unroll 4
    for (int k = 0; k < 64; ++k) {
        float na = srows[k][a] * rn2[k];
        const float* rbp = &srows[k][b0];
#pragma unroll
        for (int i = 0; i < 16; ++i) acc[i] = fmaf(na, rbp[i], acc[i]);
    }
#pragma unroll
    for (int i = 0; i < 16; ++i)
        ws[WS_GP + ob * 4096 + a * 64 + b0 + i] = acc[i];   // own slot, no atomic
}

#define MFMA_F16 __builtin_amdgcn_mfma_f32_16x16x32_f16

// 2048 blocks x 256 thr. Block = (row-group of 64, K-split of 256 codes).
// Wave = 16 rows x 256 codes; fp16x2 4-term MFMA emulation.
// Top-2 tracking via index-embedded monotone u32 keys: state = sa/ua/m1/m2
// = 16 regs; total demand ~58 <= the 8-wave 64-reg unified budget -> no
// AGPR shuttle. BEST-MEASURED session variant (119.3 us total); r12-r15
// structural alternatives (ping-pong, lockstep, LDS staging, full-K
// fusion) all neutral-to-negative.
__global__ __launch_bounds__(256)
void vq_main(const float* __restrict__ inp, float* __restrict__ ws) {
    const int t    = threadIdx.x;
    const int lane = t & 63;
    const int wave = t >> 6;
    const int col  = lane & 15;
    const int kg   = lane >> 4;
    const int rg   = blockIdx.x >> 2;      // row group 0..511 (64 rows)
    const int sp   = blockIdx.x & 3;       // k split 0..3 (256 codes)
    const int row  = rg * 64 + wave * 16 + col;

    // A-frags: hi/mid per k-step
    f16x8 xh0, xm0, xh1, xm1;
    {
        const float* xp = inp + (size_t)row * D_DIM + kg * 8;
        float4 A4 = *(const float4*)xp;
        float4 B4 = *(const float4*)(xp + 4);
        float v[8] = {A4.x, A4.y, A4.z, A4.w, B4.x, B4.y, B4.z, B4.w};
        decomp2x8(v, xh0, xm0);
        A4 = *(const float4*)(xp + 32);
        B4 = *(const float4*)(xp + 36);
        float w[8] = {A4.x, A4.y, A4.z, A4.w, B4.x, B4.y, B4.z, B4.w};
        decomp2x8(w, xh1, xm1);
    }

    const float4* EBp = (const float4*)(ws + WS_EB)
                      + (size_t)sp * MAIN_CHUNKS * CHUNK_F4;

    float sa[4], ua[4];
    unsigned m1[4], m2[4];
#pragma unroll
    for (int q = 0; q < 4; ++q) {
        sa[q] = 0.f; ua[q] = 0.f;
        m1[q] = 0u; m2[q] = 0u;     // below any finite key
    }

#pragma unroll 1
    for (int c = 0; c < MAIN_CHUNKS; ++c) {
        const float4* p = EBp + (size_t)c * CHUNK_F4;
        const f16x8* pb = (const f16x8*)p;
        f16x8 bh0 = pb[0 * 64 + lane];     // hi,  k-step 0
        f16x8 bm0 = pb[1 * 64 + lane];     // mid, k-step 0
        f16x8 bh1 = pb[2 * 64 + lane];     // hi,  k-step 1
        f16x8 bm1 = pb[3 * 64 + lane];     // mid, k-step 1
        const float e2v = ((const float*)(p + 256))[col];

        f32x4 acc = {0.f, 0.f, 0.f, 0.f};
        acc = MFMA_F16(xh0, bh0, acc, 0, 0, 0);
        acc = MFMA_F16(xh1, bh1, acc, 0, 0, 0);
        acc = MFMA_F16(xm0, bh0, acc, 0, 0, 0);
        acc = MFMA_F16(xm1, bh1, acc, 0, 0, 0);
        acc = MFMA_F16(xh0, bm0, acc, 0, 0, 0);
        acc = MFMA_F16(xh1, bm1, acc, 0, 0, 0);
        acc = MFMA_F16(xm0, bm0, acc, 0, 0, 0);
        acc = MFMA_F16(xm1, bm1, acc, 0, 0, 0);

        // embed value: same for all q (code = c*16+col, split-local, 8 bits);
        // inverted so smaller code -> larger key -> legacy first-index ties
        const unsigned embedv = 255u - (unsigned)(c * 16 + col);
#pragma unroll
        for (int q = 0; q < 4; ++q) {
            // base-2 shifted logit: g = 2*log2e*dot - log2e*(e2+C_SHIFT)
            float g = fmaf(2.0f * LOG2E_F, acc[q], -e2v);
            float pw;
            asm("v_exp_f32 %0, %1" : "=v"(pw) : "v"(g));   // 2^g
            sa[q] += pw;
            ua[q] = fmaf(pw, g, ua[q]);
            // monotone key with embedded code (low-8 clear = <=1e-3 perturb,
            // screened by TAU with 60x margin in combine)
            int gb = __float_as_int(g);
            unsigned u = (unsigned)(gb ^ ((gb >> 31) | 0x80000000));
            unsigned key = (u & 0xFFFFFF00u) | embedv;
            m2[q] = uminu(umaxu(key, m2[q]), m1[q]);   // med3(key, m2, m1)
            m1[q] = umaxu(m1[q], key);
        }
    }

    // per-row reduce across the 16 lanes sharing each C-row:
    // branch-free 2-way sorted-pair merge on keys
#pragma unroll
    for (int off = 1; off < 16; off <<= 1) {
#pragma unroll
        for (int q = 0; q < 4; ++q) {
            sa[q] += __shfl_xor(sa[q], off);
            ua[q] += __shfl_xor(ua[q], off);
            unsigned p1 = (unsigned)__shfl_xor((int)m1[q], off);
            unsigned p2 = (unsigned)__shfl_xor((int)m2[q], off);
            unsigned lo = uminu(m1[q], p1);
            m1[q] = umaxu(m1[q], p1);
            m2[q] = umaxu(lo, umaxu(m2[q], p2));
        }
    }

    if (col == 0) {
#pragma unroll
        for (int q = 0; q < 4; ++q) {
            const int r  = rg * 64 + wave * 16 + kg * 4 + q;
            const int pi = sp * N_ROWS + r;
            ws[WS_PART_S  + pi] = sa[q];
            ws[WS_PART_U  + pi] = ua[q];
            ws[WS_PART_M1 + pi] = __uint_as_float(m1[q]);
            ws[WS_PART_M2 + pi] = __uint_as_float(m2[q]);
        }
    }
}

// 512 blocks x 256 thr; QUAD (4 lanes) per row. Zero global atomics.
// Candidates decoded straight from the keys.
__global__ __launch_bounds__(256) void vq_combine(const float* __restrict__ inp,
                                                  const float* __restrict__ emb,
                                                  float* __restrict__ ws,
                                                  float* __restrict__ out) {
    __shared__ float shH[4], shC[4];
    const int t    = threadIdx.x;
    const int lane = t & 63;
    const int wave = t >> 6;
    const int l    = t & 3;               // quad lane = chain id
    const int row  = blockIdx.x * 64 + (t >> 2);
    const int qb   = lane & ~3;           // quad base within wave

    // this lane's split-l partials
    const int pi = l * N_ROWS + row;
    float    Sl = ws[WS_PART_S  + pi];
    float    Ul = ws[WS_PART_U  + pi];
    unsigned K1 = __float_as_uint(ws[WS_PART_M1 + pi]);
    unsigned K2 = __float_as_uint(ws[WS_PART_M2 + pi]);
    float    G1 = keyval(K1);

    // quad gather: S,U in ascending split order (legacy); Gmax over splits
    float S = 0.f, U2 = 0.f, Gmax = -1e30f;
#pragma unroll
    for (int k = 0; k < 4; ++k) {
        S  += __shfl(Sl, qb + k);
        U2 += __shfl(Ul, qb + k);
        Gmax = fmaxf(Gmax, __shfl(G1, qb + k));
    }

    // X strided quarter: Xq[k] = X[l + 4k] (serves chains + write + commit)
    float4 Xq[4];
    const float4* xr = (const float4*)(inp + (size_t)row * D_DIM);
#pragma unroll
    for (int k = 0; k < 4; ++k) Xq[k] = xr[l + 4 * k];

    // candidates in legacy order j=0..7 (split asc, rank-1 before rank-2)
    float bestg = -1e30f; int I = K_CODES;
#pragma unroll 1
    for (int j = 0; j < 8; ++j) {
        const int sp = j >> 1;
        const unsigned kk = (unsigned)__shfl((int)((j & 1) ? K2 : K1), qb + sp);
        const float v = keyval(kk);
        if (v < Gmax - TAU) continue;      // provably cannot be exact argmax
        const int c = sp * 256 + 255 - (int)(kk & 255u);
        // lane l: legacy chain d_l = fma chain over e4[l+4k] x X[l+4k]
        const float4* e4 = (const float4*)(emb + (size_t)c * D_DIM);
        float d = 0.f;
#pragma unroll
        for (int k = 0; k < 4; ++k) {
            float4 ev = e4[l + 4 * k];
            float4 xv = Xq[k];
            d = fmaf(ev.x, xv.x, d); d = fmaf(ev.y, xv.y, d);
            d = fmaf(ev.z, xv.z, d); d = fmaf(ev.w, xv.w, d);
        }
        float dA = __shfl(d, qb + 0) + __shfl(d, qb + 1);   // (d0+d1)
        float dB = __shfl(d, qb + 2) + __shfl(d, qb + 3);   // (d2+d3)
        float g  = fmaf(2.0f, dA + dB, -ws[WS_E2C + c]);    // legacy-exact
        if (g > bestg || (g == bestg && c < I)) { bestg = g; I = c; }
    }

    float H = logf(S) - (U2 * LN2_F) / S;  // per-row entropy (nats)

    if (l == 0) out[OUT_IDX + row] = (float)I;

    // quantized + commitment on the strided quarter (elementwise-identical Q)
    const float4* q4 = (const float4*)(emb + (size_t)I * D_DIM);
    float4* oq = (float4*)out + (size_t)row * 16;
    float cs = 0.f;
#pragma unroll
    for (int k = 0; k < 4; ++k) {
        float4 q = q4[l + 4 * k], x = Xq[k];
        float dx = q.x - x.x, dy = q.y - x.y, dz = q.z - x.z, dw = q.w - x.w;
        cs += dx * dx + dy * dy + dz * dz + dw * dw;
        float4 o;
        o.x = x.x + dx; o.y = x.y + dy; o.z = x.z + dz; o.w = x.w + dw;
        oq[l + 4 * k] = o;
    }

    float Hc = (l == 0) ? H : 0.f;
#pragma unroll
    for (int off = 32; off; off >>= 1) {
        Hc += __shfl_down(Hc, off);
        cs += __shfl_down(cs, off);
    }
    if (lane == 0) { shH[wave] = Hc; shC[wave] = cs; }
    __syncthreads();
    if (t == 0) {
        ws[WS_PH + blockIdx.x] = shH[0] + shH[1] + shH[2] + shH[3];
        ws[WS_PC + blockIdx.x] = shC[0] + shC[1] + shC[2] + shC[3];
    }
}

// 16 blocks x 256 thr; block b LDS-histograms rows [2048b, 2048b+2048) from
// OUT_IDX, writes its 1024-bucket partial to a private slot. No global atomics.
__global__ __launch_bounds__(256) void vq_hist(const float* __restrict__ out,
                                               float* __restrict__ ws) {
    __shared__ int h[K_CODES];
    const int t = threadIdx.x;
#pragma unroll
    for (int i = 0; i < 4; ++i) h[t + 256 * i] = 0;
    __syncthreads();
    const int base = blockIdx.x * 2048;
#pragma unroll
    for (int i = 0; i < 8; ++i) {
        int idx = (int)out[OUT_IDX + base + t + 256 * i];
        atomicAdd(&h[idx], 1);                          // LDS atomic only
    }
    __syncthreads();
#pragma unroll
    for (int i = 0; i < 4; ++i) {
        const int k = t + 256 * i;
        ws[WS_HB + blockIdx.x * K_CODES + k] = (float)h[k];
    }
}

// 1 block x 256 thr. Plain loads only: every input written by prior dispatches.
__global__ __launch_bounds__(256) void vq_finalize(const float* __restrict__ ws,
                                                   const float* __restrict__ cc,
                                                   float* __restrict__ out) {
    __shared__ float red[5][4];
    const int t = threadIdx.x;
    float hp = 0.f, gg = 0.f, nu = 0.f, hh = 0.f, cm = 0.f;
    for (int k = t; k < K_CODES; k += 256) {
        float s = 0.f;
#pragma unroll
        for (int b = 0; b < 16; ++b) s += ws[WS_HB + b * K_CODES + k];
        float p = s * (1.0f / (float)N_ROWS);
        hp += p * logf(p + 1e-10f);
        nu += (cc[k] >= 1.0f) ? 1.0f : 0.0f;
    }
    for (int i = t; i < 4096; i += 256) {
        float s = 0.f;
#pragma unroll
        for (int b = 0; b < 16; ++b) s += ws[WS_GP + b * 4096 + i];
        gg = fmaf(s, s, gg);
    }
    for (int i = t; i < 512; i += 256) {
        hh += ws[WS_PH + i];
        cm += ws[WS_PC + i];
    }
#pragma unroll
    for (int off = 32; off; off >>= 1) {
        hp += __shfl_down(hp, off);
        gg += __shfl_down(gg, off);
        nu += __shfl_down(nu, off);
        hh += __shfl_down(hh, off);
        cm += __shfl_down(cm, off);
    }
    if ((t & 63) == 0) {
        const int w = t >> 6;
        red[0][w] = hp; red[1][w] = gg; red[2][w] = nu;
        red[3][w] = hh; red[4][w] = cm;
    }
    __syncthreads();
    if (t == 0) {
        float hsum = red[0][0] + red[0][1] + red[0][2] + red[0][3];
        float gsum = red[1][0] + red[1][1] + red[1][2] + red[1][3];
        float nuv  = red[2][0] + red[2][1] + red[2][2] + red[2][3];
        float hacc = red[3][0] + red[3][1] + red[3][2] + red[3][3];
        float cacc = red[4][0] + red[4][1] + red[4][2] + red[4][3];
        out[OUT_PERP]   = expf(-hsum);
        out[OUT_ENT]    = hacc * (1.0f / (float)N_ROWS) * 0.1f; // /log2(1024)
        out[OUT_COMMIT] = cacc * (1.0f / ((float)N_ROWS * (float)D_DIM));
        out[OUT_ORTHO]  = gsum / (nuv * nuv) - 1.0f / nuv;
        out[OUT_COV]    = nuv * (1.0f / (float)K_CODES);
    }
}

extern "C" void kernel_launch(void* const* d_in, const int* in_sizes, int n_in,
                              void* d_out, int out_size, void* d_ws, size_t ws_size,
                              hipStream_t stream) {
    const float* inp = (const float*)d_in[0];   // [16,2048,64]
    const float* emb = (const float*)d_in[1];   // [1024,64]
    const float* cc  = (const float*)d_in[2];   // [1024]
    float* out = (float*)d_out;
    float* ws  = (float*)d_ws;

    vq_prep_ortho<<<32, 256, 0, stream>>>(emb, cc, ws);
    vq_main<<<(N_ROWS / 64) * NSPLIT, 256, 0, stream>>>(inp, ws);
    vq_combine<<<N_ROWS / 64, 256, 0, stream>>>(inp, emb, ws, out);
    vq_hist<<<16, 256, 0, stream>>>(out, ws);
    vq_finalize<<<1, 256, 0, stream>>>(ws, cc, out);
}